// Round 6
// baseline (215.899 us; speedup 1.0000x reference)
//
#include <hip/hip_runtime.h>
#include <hip/hip_bf16.h>
#include <math.h>

#define H 128
#define EPS 1e-5f
#define INF_BIAS 0.1f

typedef __attribute__((ext_vector_type(8))) short bf16x8;
typedef __attribute__((ext_vector_type(4))) float f32x4;

// ---- bf16 helpers (RNE) ----
__device__ inline unsigned short f2bf_rne(float f) {
    unsigned u = __float_as_uint(f);
    u += 0x7fffu + ((u >> 16) & 1u);
    return (unsigned short)(u >> 16);
}
__device__ inline float bf2f(unsigned short h) {
    return __uint_as_float(((unsigned)h) << 16);
}
__device__ inline unsigned pack2(float a, float b) {
    return (unsigned)f2bf_rne(a) | ((unsigned)f2bf_rne(b) << 16);
}
__device__ inline float2 unpack2(unsigned v) {
    float2 r;
    r.x = __uint_as_float(v << 16);
    r.y = __uint_as_float(v & 0xffff0000u);
    return r;
}

// ---------------------------------------------------------------------------
// prep: BN-prescaled bf16 W in MFMA A-fragment order with PERMUTED j->m
// mapping (epilogue contiguity). Unchanged math from prior rounds.
// ---------------------------------------------------------------------------
__global__ void prep_kernel(
    const float* __restrict__ W1, const float* __restrict__ b1,
    const float* __restrict__ gamma, const float* __restrict__ beta,
    const float* __restrict__ rm, const float* __restrict__ rv,
    unsigned short* __restrict__ Wswz_u, unsigned short* __restrict__ Wswz_f,
    float* __restrict__ d_user)
{
    const int f    = blockIdx.x;          // 0..31
    const int half = f >> 4, nt = (f >> 2) & 3, kt = f & 3;
    const int t    = threadIdx.x;         // 0..63
    const int c    = t & 15, q = t >> 4;

    const int j  = half * 64 + (c >> 2) * 16 + nt * 4 + (c & 3);
    const float a = gamma[j] * rsqrtf(rv[j] + EPS);
    const int k0 = kt * 32 + q * 8;

    unsigned short wu[8], wf[8];
    #pragma unroll
    for (int i = 0; i < 8; ++i) {
        wu[i] = f2bf_rne(a * W1[(size_t)j * (2 * H) + k0 + i]);
        wf[i] = f2bf_rne(a * W1[(size_t)j * (2 * H) + H + k0 + i]);
    }
    const size_t dst = (size_t)f * 512 + (size_t)t * 8;   // ushort units
    #pragma unroll
    for (int i = 0; i < 8; ++i) { Wswz_u[dst + i] = wu[i]; Wswz_f[dst + i] = wf[i]; }

    if (kt == 0 && q == 0) d_user[j] = a * (b1[j] - rm[j]) + beta[j];
}

// ---------------------------------------------------------------------------
// proj_mfma v9: ONE wave per 16-row tile computing ALL 128 output columns.
// R5 post-mortem: the old wave-pair design read every Z row TWICE (154 MB)
// and duplicated the hi/lo split-precision cvt VALU; with 8 waves/CU and
// 1-ahead prefetch (~450cy cover vs ~900cy HBM latency) it was also poorly
// latency-hidden. v9: W fragments (32 KB/mode) staged once into LDS per
// block, read per-kt via conflict-free ds_read_b128; Z read once (77 MB);
// freed VGPRs buy a 3-buffer 2-iterations-ahead Z prefetch. Per-fragment
// MFMA sequence, operands, acc order, and store bytes are the exact union
// of the old wave-pair's -> bit-identical output.
// ---------------------------------------------------------------------------
__global__ __launch_bounds__(256, 2) void proj_mfma(
    const float* __restrict__ z_user, const float* __restrict__ z_food,
    const unsigned short* __restrict__ Wswz_u, const unsigned short* __restrict__ Wswz_f,
    const float* __restrict__ d_user,
    unsigned short* __restrict__ U, unsigned short* __restrict__ F,
    int n_users, int n_foods, int GU, int GB)
{
    __shared__ unsigned short Wlds[32 * 512];   // 32 KB: one mode's 32 fragments

    const bool userMode = (blockIdx.x < (unsigned)GU);
    const float* Z;
    const unsigned short* Wsrc;
    unsigned short* Out;
    int n, blk0, nblk;
    if (userMode) { Z = z_user; Wsrc = Wswz_u; Out = U; n = n_users; blk0 = blockIdx.x;      nblk = GU; }
    else          { Z = z_food; Wsrc = Wswz_f; Out = F; n = n_foods; blk0 = blockIdx.x - GU; nblk = GB - GU; }
    const int tiles = n >> 4;               // n divisible by 16

    // stage this mode's W fragments into LDS once per block (coalesced)
    {
        const uint4* src = (const uint4*)Wsrc;
        uint4* dst = (uint4*)Wlds;
        #pragma unroll
        for (int i = 0; i < 8; ++i)
            dst[threadIdx.x + i * 256] = src[threadIdx.x + i * 256];
    }
    __syncthreads();

    const int wave = threadIdx.x >> 6;
    const int lane = threadIdx.x & 63;
    const int c = lane & 15;                // row within tile
    const int q = lane >> 4;                // k-group / 16-col subgroup
    const int wg = blk0 * 4 + wave;         // tile id start (1 wave : 1 tile)
    const int stride = nblk * 4;            // tile stride between iterations

    // ---- BN offset (accumulator init values), both halves
    f32x4 dvec[8];
    #pragma unroll
    for (int hn = 0; hn < 8; ++hn) {
        if (userMode) {
            // hn = h*4 + nt -> column group h*64 + q*16 + nt*4
            float4 d = *(const float4*)(d_user + (hn >> 2) * 64 + q * 16 + (hn & 3) * 4);
            dvec[hn] = (f32x4){d.x, d.y, d.z, d.w};
        } else {
            dvec[hn] = (f32x4){0.f, 0.f, 0.f, 0.f};
        }
    }

    // ---- Z tile load (clamped address; 8 x 16B per lane, full 512B row x16)
    auto loadZ = [&](int t, float4 zb[8]) {
        const float* zrow = Z + (size_t)(min(t, tiles - 1) * 16 + c) * H;
        #pragma unroll
        for (int kt = 0; kt < 4; ++kt) {
            const int k0 = kt * 32 + q * 8;
            zb[2 * kt + 0] = ((const float4*)(zrow + k0))[0];
            zb[2 * kt + 1] = ((const float4*)(zrow + k0))[1];
        }
    };

    // ---- compute + guarded store (per-fragment math identical to v8)
    auto computeStore = [&](int t, const float4 zb[8]) {
        f32x4 acc[8];
        #pragma unroll
        for (int hn = 0; hn < 8; ++hn) acc[hn] = dvec[hn];

        #pragma unroll
        for (int kt = 0; kt < 4; ++kt) {
            float4 za = zb[2 * kt + 0];
            float4 zv = zb[2 * kt + 1];
            bf16x8 zhi, zlo;
            {
                float v[8] = {za.x, za.y, za.z, za.w, zv.x, zv.y, zv.z, zv.w};
                #pragma unroll
                for (int i = 0; i < 8; ++i) {
                    unsigned short hi = f2bf_rne(v[i]);
                    unsigned short lo = f2bf_rne(v[i] - bf2f(hi));
                    zhi[i] = (short)hi; zlo[i] = (short)lo;
                }
            }
            #pragma unroll
            for (int hn = 0; hn < 8; ++hn) {
                const int frag = (hn >> 2) * 16 + (hn & 3) * 4 + kt;
                bf16x8 wfrag = *(const bf16x8*)(Wlds + (size_t)frag * 512 + lane * 8);
                acc[hn] = __builtin_amdgcn_mfma_f32_16x16x32_bf16(wfrag, zhi, acc[hn], 0, 0, 0);
                acc[hn] = __builtin_amdgcn_mfma_f32_16x16x32_bf16(wfrag, zlo, acc[hn], 0, 0, 0);
            }
        }

        if (t < tiles) {
            const int r = t * 16 + c;
            unsigned short* obase = Out + (size_t)r * H + q * 16;   // half 0
            uint4 p0, p1, p2, p3;
            p0.x = pack2(acc[0][0], acc[0][1]); p0.y = pack2(acc[0][2], acc[0][3]);
            p0.z = pack2(acc[1][0], acc[1][1]); p0.w = pack2(acc[1][2], acc[1][3]);
            p1.x = pack2(acc[2][0], acc[2][1]); p1.y = pack2(acc[2][2], acc[2][3]);
            p1.z = pack2(acc[3][0], acc[3][1]); p1.w = pack2(acc[3][2], acc[3][3]);
            p2.x = pack2(acc[4][0], acc[4][1]); p2.y = pack2(acc[4][2], acc[4][3]);
            p2.z = pack2(acc[5][0], acc[5][1]); p2.w = pack2(acc[5][2], acc[5][3]);
            p3.x = pack2(acc[6][0], acc[6][1]); p3.y = pack2(acc[6][2], acc[6][3]);
            p3.z = pack2(acc[7][0], acc[7][1]); p3.w = pack2(acc[7][2], acc[7][3]);
            *(uint4*)(obase)          = p0;
            *(uint4*)(obase + 8)      = p1;
            *(uint4*)(obase + 64)     = p2;     // half 1: +64 cols
            *(uint4*)(obase + 64 + 8) = p3;
        }
    };

    int nIt = (tiles + stride - 1) / stride;
    nIt = ((nIt + 2) / 3) * 3;              // multiple of 3 for 3-stage pipeline

    // 3-buffer rotation: loads issued 2 iterations ahead of use (~2x HBM
    // latency cover at ~450-900cy compute per tile)
    float4 zb0[8], zb1[8], zb2[8];
    int t = wg;
    loadZ(t, zb0);
    loadZ(t + stride, zb1);
    for (int it = 0; it < nIt; it += 3) {
        loadZ(t + 2 * stride, zb2);
        computeStore(t, zb0);
        loadZ(t + 3 * stride, zb0);
        computeStore(t + stride, zb1);
        loadZ(t + 4 * stride, zb1);
        computeStore(t + 2 * stride, zb2);
        t += 3 * stride;
    }
}

// ---------------------------------------------------------------------------
// edge kernel (round-4 best config, reverted): 8-deep gather pipeline,
// 8192 blocks. R4/R5 A/B showed the gather is THROUGHPUT-saturated on the
// L2-miss path (~230 MB at ~3.5 TB/s regardless of MLP depth or residency);
// 8192-block launch was the fastest measured (66.9 us).
// ---------------------------------------------------------------------------
#define EUN 8
__global__ __launch_bounds__(256, 4) void edge_kernel(
    const unsigned short* __restrict__ U, const unsigned short* __restrict__ F,
    const int* __restrict__ row, const int* __restrict__ col,
    const float* __restrict__ W2, const float* __restrict__ b2,
    float* __restrict__ out, int E)
{
    const int lane = threadIdx.x & 15;
    const int g  = (blockIdx.x * blockDim.x + threadIdx.x) >> 4;
    const int nG = (gridDim.x * blockDim.x) >> 4;

    const float4 w2a = ((const float4*)W2)[2 * lane];
    const float4 w2b = ((const float4*)W2)[2 * lane + 1];
    const float bias = b2[0] + INF_BIAS;

    for (int e0 = g; e0 < E; e0 += EUN * nG) {
        int iu[EUN], ifo[EUN];
        #pragma unroll
        for (int i = 0; i < EUN; ++i) {
            int e  = e0 + i * nG;
            int ec = (e < E) ? e : e0;
            iu[i]  = row[ec];
            ifo[i] = col[ec];
        }
        uint4 uv[EUN], fv[EUN];
        #pragma unroll
        for (int i = 0; i < EUN; ++i) {
            uv[i] = ((const uint4*)(U + (size_t)iu[i]  * H))[lane];
            fv[i] = ((const uint4*)(F + (size_t)ifo[i] * H))[lane];
        }
        #pragma unroll
        for (int i = 0; i < EUN; ++i) {
            float2 u0 = unpack2(uv[i].x), f0 = unpack2(fv[i].x);
            float2 u1 = unpack2(uv[i].y), f1 = unpack2(fv[i].y);
            float2 u2 = unpack2(uv[i].z), f2 = unpack2(fv[i].z);
            float2 u3 = unpack2(uv[i].w), f3 = unpack2(fv[i].w);

            float s =
                w2a.x * fmaxf(u0.x + f0.x, 0.0f) +
                w2a.y * fmaxf(u0.y + f0.y, 0.0f) +
                w2a.z * fmaxf(u1.x + f1.x, 0.0f) +
                w2a.w * fmaxf(u1.y + f1.y, 0.0f) +
                w2b.x * fmaxf(u2.x + f2.x, 0.0f) +
                w2b.y * fmaxf(u2.y + f2.y, 0.0f) +
                w2b.z * fmaxf(u3.x + f3.x, 0.0f) +
                w2b.w * fmaxf(u3.y + f3.y, 0.0f);

            s += __shfl_xor(s, 8, 16);
            s += __shfl_xor(s, 4, 16);
            s += __shfl_xor(s, 2, 16);
            s += __shfl_xor(s, 1, 16);

            const int e = e0 + i * nG;
            if (lane == 0 && e < E) {
                float x = s + bias;
                out[e] = 1.0f / (1.0f + __expf(-x));
            }
        }
    }
}

extern "C" void kernel_launch(void* const* d_in, const int* in_sizes, int n_in,
                              void* d_out, int out_size, void* d_ws, size_t ws_size,
                              hipStream_t stream) {
    const float* z_user = (const float*)d_in[0];
    const float* z_food = (const float*)d_in[1];
    const int*   row    = (const int*)d_in[2];
    const int*   col    = (const int*)d_in[3];
    const float* W1     = (const float*)d_in[4];
    const float* b1     = (const float*)d_in[5];
    const float* gamma  = (const float*)d_in[6];
    const float* beta   = (const float*)d_in[7];
    const float* rm     = (const float*)d_in[8];
    const float* rv     = (const float*)d_in[9];
    const float* W2     = (const float*)d_in[10];
    const float* b2     = (const float*)d_in[11];
    float* out = (float*)d_out;

    const int n_users = in_sizes[0] / H;
    const int n_foods = in_sizes[1] / H;
    const int E       = in_sizes[2];

    // workspace layout
    unsigned short* U      = (unsigned short*)d_ws;        // n_users*128 bf16
    unsigned short* F      = U + (size_t)n_users * H;      // n_foods*128 bf16
    unsigned short* Wswz_u = F + (size_t)n_foods * H;      // 128*128 bf16, frag order
    unsigned short* Wswz_f = Wswz_u + H * H;               // 128*128 bf16, frag order
    float*          d_usr  = (float*)(Wswz_f + H * H);     // 128 f32

    prep_kernel<<<32, 64, 0, stream>>>(W1, b1, gamma, beta, rm, rv,
                                       Wswz_u, Wswz_f, d_usr);

    // persistent: ~2 blocks/CU, 2:1 user:food split matches row ratio
    const int GU = 342, GB = 512;
    proj_mfma<<<GB, 256, 0, stream>>>(z_user, z_food, Wswz_u, Wswz_f, d_usr,
                                      U, F, n_users, n_foods, GU, GB);

    edge_kernel<<<8192, 256, 0, stream>>>(U, F, row, col, W2, b2, out, E);
}

// Round 7
// 209.943 us; speedup vs baseline: 1.0284x; 1.0284x over previous
//
#include <hip/hip_runtime.h>
#include <hip/hip_bf16.h>
#include <math.h>

#define H 128
#define EPS 1e-5f
#define INF_BIAS 0.1f

typedef __attribute__((ext_vector_type(8))) short bf16x8;
typedef __attribute__((ext_vector_type(4))) float f32x4;

// ---- bf16 helpers (RNE) ----
__device__ inline unsigned short f2bf_rne(float f) {
    unsigned u = __float_as_uint(f);
    u += 0x7fffu + ((u >> 16) & 1u);
    return (unsigned short)(u >> 16);
}
__device__ inline float bf2f(unsigned short h) {
    return __uint_as_float(((unsigned)h) << 16);
}
__device__ inline unsigned pack2(float a, float b) {
    return (unsigned)f2bf_rne(a) | ((unsigned)f2bf_rne(b) << 16);
}
__device__ inline float2 unpack2(unsigned v) {
    float2 r;
    r.x = __uint_as_float(v << 16);
    r.y = __uint_as_float(v & 0xffff0000u);
    return r;
}

// ---------------------------------------------------------------------------
// proj_mfma v10: v8 wave-pair structure VERBATIM (best measured: 206.4 us
// total), with prep fused in. R6 post-mortem: v9's LDS-staged W put 32
// ds_read_b128 (~384cy) on the per-tile MFMA critical path (~320cy) -> +9us;
// the Z double-read it saved was cheap (HBM-streamed, prefetch-covered).
// v10 keeps W fragments in registers; each wave computes its 16 fragments
// and its dvec ON THE FLY from W1/gamma/beta/rm/rv using the IDENTICAL
// instruction sequence prep_kernel used (same op order, same rsqrtf) ->
// bit-identical values, one-time ~700 VALU cy per persistent wave (~1-2%
// of lifetime, hidden under first Z loads). Saves the prep dispatch + one
// launch gap; workspace shrinks to U,F only.
// ---------------------------------------------------------------------------
__global__ __launch_bounds__(256, 2) void proj_mfma(
    const float* __restrict__ z_user, const float* __restrict__ z_food,
    const float* __restrict__ W1, const float* __restrict__ b1,
    const float* __restrict__ gamma, const float* __restrict__ beta,
    const float* __restrict__ rm, const float* __restrict__ rv,
    unsigned short* __restrict__ U, unsigned short* __restrict__ F,
    int n_users, int n_foods, int GU, int GB)
{
    const bool userMode = (blockIdx.x < (unsigned)GU);
    const float* Z;
    unsigned short* Out;
    int n, blk0, nblk;
    if (userMode) { Z = z_user; Out = U; n = n_users; blk0 = blockIdx.x;      nblk = GU; }
    else          { Z = z_food; Out = F; n = n_foods; blk0 = blockIdx.x - GU; nblk = GB - GU; }
    const int tiles = n >> 4;               // n divisible by 16

    const int wave = threadIdx.x >> 6;
    const int lane = threadIdx.x & 63;
    const int c = lane & 15;                // row within tile
    const int q = lane >> 4;                // k-group / 16-col subgroup
    const int wg   = blk0 * 4 + wave;       // global wave id within mode
    const int half = wg & 1;                // 64-col half
    const int pair = wg >> 1;               // tile-pair id
    const int stride = nblk * 2;            // tile stride between iterations

    // ---- fused prep: this wave's 16 W fragments, computed in-register.
    // Bit-identical to the old prep_kernel values (same ops, same order):
    // wf[nt][kt][i] = f2bf_rne(a_j * W1[j][kbase + kt*32 + q*8 + i]),
    // j = half*64 + (c>>2)*16 + nt*4 + (c&3), a_j = gamma[j]*rsqrtf(rv[j]+EPS)
    const int kbase = userMode ? 0 : H;
    bf16x8 wf[4][4];
    #pragma unroll
    for (int nt = 0; nt < 4; ++nt) {
        const int j = half * 64 + (c >> 2) * 16 + nt * 4 + (c & 3);
        const float a = gamma[j] * rsqrtf(rv[j] + EPS);
        #pragma unroll
        for (int kt = 0; kt < 4; ++kt) {
            const float* wp = W1 + (size_t)j * (2 * H) + kbase + kt * 32 + q * 8;
            float4 wA = ((const float4*)wp)[0];
            float4 wB = ((const float4*)wp)[1];
            bf16x8 w;
            w[0] = (short)f2bf_rne(a * wA.x); w[1] = (short)f2bf_rne(a * wA.y);
            w[2] = (short)f2bf_rne(a * wA.z); w[3] = (short)f2bf_rne(a * wA.w);
            w[4] = (short)f2bf_rne(a * wB.x); w[5] = (short)f2bf_rne(a * wB.y);
            w[6] = (short)f2bf_rne(a * wB.z); w[7] = (short)f2bf_rne(a * wB.w);
            wf[nt][kt] = w;
        }
    }

    // ---- fused BN offset (accumulator init), computed like old d_user[j]:
    // d[j] = a_j*(b1[j]-rm[j]) + beta[j], j = half*64 + q*16 + nt*4 + m
    f32x4 dvec[4];
    #pragma unroll
    for (int nt = 0; nt < 4; ++nt) {
        if (userMode) {
            #pragma unroll
            for (int m = 0; m < 4; ++m) {
                const int j = half * 64 + q * 16 + nt * 4 + m;
                const float a = gamma[j] * rsqrtf(rv[j] + EPS);
                dvec[nt][m] = a * (b1[j] - rm[j]) + beta[j];
            }
        } else {
            dvec[nt] = (f32x4){0.f, 0.f, 0.f, 0.f};
        }
    }

    // ---- Z tile load (clamped address; 8 x 16B per lane)
    auto loadZ = [&](int t, float4 zb[8]) {
        const float* zrow = Z + (size_t)(min(t, tiles - 1) * 16 + c) * H;
        #pragma unroll
        for (int kt = 0; kt < 4; ++kt) {
            const int k0 = kt * 32 + q * 8;
            zb[2 * kt + 0] = ((const float4*)(zrow + k0))[0];
            zb[2 * kt + 1] = ((const float4*)(zrow + k0))[1];
        }
    };

    // ---- compute + guarded store (bit-identical per-tile math to v8)
    auto computeStore = [&](int t, const float4 zb[8]) {
        f32x4 acc[4];
        #pragma unroll
        for (int nt = 0; nt < 4; ++nt) acc[nt] = dvec[nt];

        #pragma unroll
        for (int kt = 0; kt < 4; ++kt) {
            float4 za = zb[2 * kt + 0];
            float4 zv = zb[2 * kt + 1];
            bf16x8 zhi, zlo;
            {
                float v[8] = {za.x, za.y, za.z, za.w, zv.x, zv.y, zv.z, zv.w};
                #pragma unroll
                for (int i = 0; i < 8; ++i) {
                    unsigned short hi = f2bf_rne(v[i]);
                    unsigned short lo = f2bf_rne(v[i] - bf2f(hi));
                    zhi[i] = (short)hi; zlo[i] = (short)lo;
                }
            }
            #pragma unroll
            for (int nt = 0; nt < 4; ++nt) {
                acc[nt] = __builtin_amdgcn_mfma_f32_16x16x32_bf16(wf[nt][kt], zhi, acc[nt], 0, 0, 0);
                acc[nt] = __builtin_amdgcn_mfma_f32_16x16x32_bf16(wf[nt][kt], zlo, acc[nt], 0, 0, 0);
            }
        }

        if (t < tiles) {
            const int r = t * 16 + c;
            unsigned short* obase = Out + (size_t)r * H + half * 64 + q * 16;
            uint4 p0, p1;
            p0.x = pack2(acc[0][0], acc[0][1]); p0.y = pack2(acc[0][2], acc[0][3]);
            p0.z = pack2(acc[1][0], acc[1][1]); p0.w = pack2(acc[1][2], acc[1][3]);
            p1.x = pack2(acc[2][0], acc[2][1]); p1.y = pack2(acc[2][2], acc[2][3]);
            p1.z = pack2(acc[3][0], acc[3][1]); p1.w = pack2(acc[3][2], acc[3][3]);
            *(uint4*)(obase)     = p0;
            *(uint4*)(obase + 8) = p1;
        }
    };

    int nIt = (tiles + stride - 1) / stride;
    nIt = (nIt + 1) & ~1;                   // even, for 2x unrolled pipeline

    float4 zb0[8], zb1[8];
    int t = pair;
    loadZ(t, zb0);
    for (int it = 0; it < nIt; it += 2) {
        loadZ(t + stride, zb1);             // prefetch next while computing cur
        computeStore(t, zb0);
        if (it + 2 < nIt) loadZ(t + 2 * stride, zb0);
        computeStore(t + stride, zb1);
        t += 2 * stride;
    }
}

// ---------------------------------------------------------------------------
// edge kernel (round-4 best config, verbatim): 8-deep gather pipeline,
// 8192 blocks. R4/R5 A/B showed the gather is THROUGHPUT-saturated on the
// L2-miss path (~230 MB at ~3.5 TB/s regardless of MLP depth or residency);
// this launch config was the fastest measured (66.9 us).
// ---------------------------------------------------------------------------
#define EUN 8
__global__ __launch_bounds__(256, 4) void edge_kernel(
    const unsigned short* __restrict__ U, const unsigned short* __restrict__ F,
    const int* __restrict__ row, const int* __restrict__ col,
    const float* __restrict__ W2, const float* __restrict__ b2,
    float* __restrict__ out, int E)
{
    const int lane = threadIdx.x & 15;
    const int g  = (blockIdx.x * blockDim.x + threadIdx.x) >> 4;
    const int nG = (gridDim.x * blockDim.x) >> 4;

    const float4 w2a = ((const float4*)W2)[2 * lane];
    const float4 w2b = ((const float4*)W2)[2 * lane + 1];
    const float bias = b2[0] + INF_BIAS;

    for (int e0 = g; e0 < E; e0 += EUN * nG) {
        int iu[EUN], ifo[EUN];
        #pragma unroll
        for (int i = 0; i < EUN; ++i) {
            int e  = e0 + i * nG;
            int ec = (e < E) ? e : e0;
            iu[i]  = row[ec];
            ifo[i] = col[ec];
        }
        uint4 uv[EUN], fv[EUN];
        #pragma unroll
        for (int i = 0; i < EUN; ++i) {
            uv[i] = ((const uint4*)(U + (size_t)iu[i]  * H))[lane];
            fv[i] = ((const uint4*)(F + (size_t)ifo[i] * H))[lane];
        }
        #pragma unroll
        for (int i = 0; i < EUN; ++i) {
            float2 u0 = unpack2(uv[i].x), f0 = unpack2(fv[i].x);
            float2 u1 = unpack2(uv[i].y), f1 = unpack2(fv[i].y);
            float2 u2 = unpack2(uv[i].z), f2 = unpack2(fv[i].z);
            float2 u3 = unpack2(uv[i].w), f3 = unpack2(fv[i].w);

            float s =
                w2a.x * fmaxf(u0.x + f0.x, 0.0f) +
                w2a.y * fmaxf(u0.y + f0.y, 0.0f) +
                w2a.z * fmaxf(u1.x + f1.x, 0.0f) +
                w2a.w * fmaxf(u1.y + f1.y, 0.0f) +
                w2b.x * fmaxf(u2.x + f2.x, 0.0f) +
                w2b.y * fmaxf(u2.y + f2.y, 0.0f) +
                w2b.z * fmaxf(u3.x + f3.x, 0.0f) +
                w2b.w * fmaxf(u3.y + f3.y, 0.0f);

            s += __shfl_xor(s, 8, 16);
            s += __shfl_xor(s, 4, 16);
            s += __shfl_xor(s, 2, 16);
            s += __shfl_xor(s, 1, 16);

            const int e = e0 + i * nG;
            if (lane == 0 && e < E) {
                float x = s + bias;
                out[e] = 1.0f / (1.0f + __expf(-x));
            }
        }
    }
}

extern "C" void kernel_launch(void* const* d_in, const int* in_sizes, int n_in,
                              void* d_out, int out_size, void* d_ws, size_t ws_size,
                              hipStream_t stream) {
    const float* z_user = (const float*)d_in[0];
    const float* z_food = (const float*)d_in[1];
    const int*   row    = (const int*)d_in[2];
    const int*   col    = (const int*)d_in[3];
    const float* W1     = (const float*)d_in[4];
    const float* b1     = (const float*)d_in[5];
    const float* gamma  = (const float*)d_in[6];
    const float* beta   = (const float*)d_in[7];
    const float* rm     = (const float*)d_in[8];
    const float* rv     = (const float*)d_in[9];
    const float* W2     = (const float*)d_in[10];
    const float* b2     = (const float*)d_in[11];
    float* out = (float*)d_out;

    const int n_users = in_sizes[0] / H;
    const int n_foods = in_sizes[1] / H;
    const int E       = in_sizes[2];

    // workspace layout (prep fused into proj: only the U/F tables remain)
    unsigned short* U = (unsigned short*)d_ws;             // n_users*128 bf16
    unsigned short* F = U + (size_t)n_users * H;           // n_foods*128 bf16

    // persistent: ~2 blocks/CU, 2:1 user:food split matches row ratio
    const int GU = 342, GB = 512;
    proj_mfma<<<GB, 256, 0, stream>>>(z_user, z_food, W1, b1, gamma, beta, rm, rv,
                                      U, F, n_users, n_foods, GU, GB);

    edge_kernel<<<8192, 256, 0, stream>>>(U, F, row, col, W2, b2, out, E);
}

// Round 8
// 206.346 us; speedup vs baseline: 1.0463x; 1.0174x over previous
//
#include <hip/hip_runtime.h>
#include <hip/hip_bf16.h>
#include <math.h>

#define H 128
#define EPS 1e-5f
#define INF_BIAS 0.1f

typedef __attribute__((ext_vector_type(8))) short bf16x8;
typedef __attribute__((ext_vector_type(4))) float f32x4;

// ---- bf16 helpers (RNE) ----
__device__ inline unsigned short f2bf_rne(float f) {
    unsigned u = __float_as_uint(f);
    u += 0x7fffu + ((u >> 16) & 1u);
    return (unsigned short)(u >> 16);
}
__device__ inline float bf2f(unsigned short h) {
    return __uint_as_float(((unsigned)h) << 16);
}
__device__ inline unsigned pack2(float a, float b) {
    return (unsigned)f2bf_rne(a) | ((unsigned)f2bf_rne(b) << 16);
}
__device__ inline float2 unpack2(unsigned v) {
    float2 r;
    r.x = __uint_as_float(v << 16);
    r.y = __uint_as_float(v & 0xffff0000u);
    return r;
}

// ---------------------------------------------------------------------------
// FINAL CONFIG (restored round-4 best, 206.4 us measured).
// Session findings (8 benched rounds):
//  - edge_kernel is throughput-saturated on the L2-miss/L3 path:
//    ~230 MB compulsory random-gather traffic at ~3.5 TB/s (=~67 us floor).
//    Falsified: 2x MLP depth (null), 2x residency (null), F-binning with
//    XCD chunking (FETCH -47% but flat time; aux kernels cost > savings).
//  - proj_mfma v8 (wave-pair, register W, 1-ahead prefetch) is best known;
//    LDS-staged W (-> +9us) and fused prep (-> +3.5us) both regressed.
//  - ~136-140 us of total is harness pedestal, invariant to launch count.
// ---------------------------------------------------------------------------

// prep: BN-prescaled bf16 W in MFMA A-fragment order with PERMUTED j->m
// mapping (epilogue contiguity).
__global__ void prep_kernel(
    const float* __restrict__ W1, const float* __restrict__ b1,
    const float* __restrict__ gamma, const float* __restrict__ beta,
    const float* __restrict__ rm, const float* __restrict__ rv,
    unsigned short* __restrict__ Wswz_u, unsigned short* __restrict__ Wswz_f,
    float* __restrict__ d_user)
{
    const int f    = blockIdx.x;          // 0..31
    const int half = f >> 4, nt = (f >> 2) & 3, kt = f & 3;
    const int t    = threadIdx.x;         // 0..63
    const int c    = t & 15, q = t >> 4;

    const int j  = half * 64 + (c >> 2) * 16 + nt * 4 + (c & 3);
    const float a = gamma[j] * rsqrtf(rv[j] + EPS);
    const int k0 = kt * 32 + q * 8;

    unsigned short wu[8], wf[8];
    #pragma unroll
    for (int i = 0; i < 8; ++i) {
        wu[i] = f2bf_rne(a * W1[(size_t)j * (2 * H) + k0 + i]);
        wf[i] = f2bf_rne(a * W1[(size_t)j * (2 * H) + H + k0 + i]);
    }
    const size_t dst = (size_t)f * 512 + (size_t)t * 8;   // ushort units
    #pragma unroll
    for (int i = 0; i < 8; ++i) { Wswz_u[dst + i] = wu[i]; Wswz_f[dst + i] = wf[i]; }

    if (kt == 0 && q == 0) d_user[j] = a * (b1[j] - rm[j]) + beta[j];
}

// proj_mfma v8: persistent wave-pairs + register double-buffered Z prefetch.
__global__ __launch_bounds__(256, 2) void proj_mfma(
    const float* __restrict__ z_user, const float* __restrict__ z_food,
    const unsigned short* __restrict__ Wswz_u, const unsigned short* __restrict__ Wswz_f,
    const float* __restrict__ d_user,
    unsigned short* __restrict__ U, unsigned short* __restrict__ F,
    int n_users, int n_foods, int GU, int GB)
{
    const bool userMode = (blockIdx.x < (unsigned)GU);
    const float* Z;
    const unsigned short* Wsrc;
    unsigned short* Out;
    int n, blk0, nblk;
    if (userMode) { Z = z_user; Wsrc = Wswz_u; Out = U; n = n_users; blk0 = blockIdx.x;      nblk = GU; }
    else          { Z = z_food; Wsrc = Wswz_f; Out = F; n = n_foods; blk0 = blockIdx.x - GU; nblk = GB - GU; }
    const int tiles = n >> 4;               // n divisible by 16

    const int wave = threadIdx.x >> 6;
    const int lane = threadIdx.x & 63;
    const int c = lane & 15;                // row within tile
    const int q = lane >> 4;                // k-group / 16-col subgroup
    const int wg   = blk0 * 4 + wave;       // global wave id within mode
    const int half = wg & 1;                // 64-col half
    const int pair = wg >> 1;               // tile-pair id
    const int stride = nblk * 2;            // tile stride between iterations

    // ---- preload this wave's 16 W fragments (64 VGPR), L2-hot
    bf16x8 wf[4][4];
    #pragma unroll
    for (int nt = 0; nt < 4; ++nt)
        #pragma unroll
        for (int kt = 0; kt < 4; ++kt)
            wf[nt][kt] = *(const bf16x8*)(Wsrc + (size_t)(half * 16 + nt * 4 + kt) * 512 + lane * 8);

    // ---- BN offset (accumulator init values)
    f32x4 dvec[4];
    #pragma unroll
    for (int nt = 0; nt < 4; ++nt) {
        if (userMode) {
            float4 d = *(const float4*)(d_user + half * 64 + q * 16 + nt * 4);
            dvec[nt] = (f32x4){d.x, d.y, d.z, d.w};
        } else {
            dvec[nt] = (f32x4){0.f, 0.f, 0.f, 0.f};
        }
    }

    // ---- Z tile load (clamped address; 8 x 16B per lane)
    auto loadZ = [&](int t, float4 zb[8]) {
        const float* zrow = Z + (size_t)(min(t, tiles - 1) * 16 + c) * H;
        #pragma unroll
        for (int kt = 0; kt < 4; ++kt) {
            const int k0 = kt * 32 + q * 8;
            zb[2 * kt + 0] = ((const float4*)(zrow + k0))[0];
            zb[2 * kt + 1] = ((const float4*)(zrow + k0))[1];
        }
    };

    // ---- compute + guarded store
    auto computeStore = [&](int t, const float4 zb[8]) {
        f32x4 acc[4];
        #pragma unroll
        for (int nt = 0; nt < 4; ++nt) acc[nt] = dvec[nt];

        #pragma unroll
        for (int kt = 0; kt < 4; ++kt) {
            float4 za = zb[2 * kt + 0];
            float4 zv = zb[2 * kt + 1];
            bf16x8 zhi, zlo;
            {
                float v[8] = {za.x, za.y, za.z, za.w, zv.x, zv.y, zv.z, zv.w};
                #pragma unroll
                for (int i = 0; i < 8; ++i) {
                    unsigned short hi = f2bf_rne(v[i]);
                    unsigned short lo = f2bf_rne(v[i] - bf2f(hi));
                    zhi[i] = (short)hi; zlo[i] = (short)lo;
                }
            }
            #pragma unroll
            for (int nt = 0; nt < 4; ++nt) {
                acc[nt] = __builtin_amdgcn_mfma_f32_16x16x32_bf16(wf[nt][kt], zhi, acc[nt], 0, 0, 0);
                acc[nt] = __builtin_amdgcn_mfma_f32_16x16x32_bf16(wf[nt][kt], zlo, acc[nt], 0, 0, 0);
            }
        }

        if (t < tiles) {
            const int r = t * 16 + c;
            unsigned short* obase = Out + (size_t)r * H + half * 64 + q * 16;
            uint4 p0, p1;
            p0.x = pack2(acc[0][0], acc[0][1]); p0.y = pack2(acc[0][2], acc[0][3]);
            p0.z = pack2(acc[1][0], acc[1][1]); p0.w = pack2(acc[1][2], acc[1][3]);
            p1.x = pack2(acc[2][0], acc[2][1]); p1.y = pack2(acc[2][2], acc[2][3]);
            p1.z = pack2(acc[3][0], acc[3][1]); p1.w = pack2(acc[3][2], acc[3][3]);
            *(uint4*)(obase)     = p0;
            *(uint4*)(obase + 8) = p1;
        }
    };

    int nIt = (tiles + stride - 1) / stride;
    nIt = (nIt + 1) & ~1;                   // even, for 2x unrolled pipeline

    float4 zb0[8], zb1[8];
    int t = pair;
    loadZ(t, zb0);
    for (int it = 0; it < nIt; it += 2) {
        loadZ(t + stride, zb1);             // prefetch next while computing cur
        computeStore(t, zb0);
        if (it + 2 < nIt) loadZ(t + 2 * stride, zb0);
        computeStore(t + stride, zb1);
        t += 2 * stride;
    }
}

// edge kernel: 8-deep gather pipeline, 8192 blocks (best measured: 66.9 us).
#define EUN 8
__global__ __launch_bounds__(256, 4) void edge_kernel(
    const unsigned short* __restrict__ U, const unsigned short* __restrict__ F,
    const int* __restrict__ row, const int* __restrict__ col,
    const float* __restrict__ W2, const float* __restrict__ b2,
    float* __restrict__ out, int E)
{
    const int lane = threadIdx.x & 15;
    const int g  = (blockIdx.x * blockDim.x + threadIdx.x) >> 4;
    const int nG = (gridDim.x * blockDim.x) >> 4;

    const float4 w2a = ((const float4*)W2)[2 * lane];
    const float4 w2b = ((const float4*)W2)[2 * lane + 1];
    const float bias = b2[0] + INF_BIAS;

    for (int e0 = g; e0 < E; e0 += EUN * nG) {
        int iu[EUN], ifo[EUN];
        #pragma unroll
        for (int i = 0; i < EUN; ++i) {
            int e  = e0 + i * nG;
            int ec = (e < E) ? e : e0;
            iu[i]  = row[ec];
            ifo[i] = col[ec];
        }
        uint4 uv[EUN], fv[EUN];
        #pragma unroll
        for (int i = 0; i < EUN; ++i) {
            uv[i] = ((const uint4*)(U + (size_t)iu[i]  * H))[lane];
            fv[i] = ((const uint4*)(F + (size_t)ifo[i] * H))[lane];
        }
        #pragma unroll
        for (int i = 0; i < EUN; ++i) {
            float2 u0 = unpack2(uv[i].x), f0 = unpack2(fv[i].x);
            float2 u1 = unpack2(uv[i].y), f1 = unpack2(fv[i].y);
            float2 u2 = unpack2(uv[i].z), f2 = unpack2(fv[i].z);
            float2 u3 = unpack2(uv[i].w), f3 = unpack2(fv[i].w);

            float s =
                w2a.x * fmaxf(u0.x + f0.x, 0.0f) +
                w2a.y * fmaxf(u0.y + f0.y, 0.0f) +
                w2a.z * fmaxf(u1.x + f1.x, 0.0f) +
                w2a.w * fmaxf(u1.y + f1.y, 0.0f) +
                w2b.x * fmaxf(u2.x + f2.x, 0.0f) +
                w2b.y * fmaxf(u2.y + f2.y, 0.0f) +
                w2b.z * fmaxf(u3.x + f3.x, 0.0f) +
                w2b.w * fmaxf(u3.y + f3.y, 0.0f);

            s += __shfl_xor(s, 8, 16);
            s += __shfl_xor(s, 4, 16);
            s += __shfl_xor(s, 2, 16);
            s += __shfl_xor(s, 1, 16);

            const int e = e0 + i * nG;
            if (lane == 0 && e < E) {
                float x = s + bias;
                out[e] = 1.0f / (1.0f + __expf(-x));
            }
        }
    }
}

extern "C" void kernel_launch(void* const* d_in, const int* in_sizes, int n_in,
                              void* d_out, int out_size, void* d_ws, size_t ws_size,
                              hipStream_t stream) {
    const float* z_user = (const float*)d_in[0];
    const float* z_food = (const float*)d_in[1];
    const int*   row    = (const int*)d_in[2];
    const int*   col    = (const int*)d_in[3];
    const float* W1     = (const float*)d_in[4];
    const float* b1     = (const float*)d_in[5];
    const float* gamma  = (const float*)d_in[6];
    const float* beta   = (const float*)d_in[7];
    const float* rm     = (const float*)d_in[8];
    const float* rv     = (const float*)d_in[9];
    const float* W2     = (const float*)d_in[10];
    const float* b2     = (const float*)d_in[11];
    float* out = (float*)d_out;

    const int n_users = in_sizes[0] / H;
    const int n_foods = in_sizes[1] / H;
    const int E       = in_sizes[2];

    // workspace layout
    unsigned short* U      = (unsigned short*)d_ws;        // n_users*128 bf16
    unsigned short* F      = U + (size_t)n_users * H;      // n_foods*128 bf16
    unsigned short* Wswz_u = F + (size_t)n_foods * H;      // 128*128 bf16, frag order
    unsigned short* Wswz_f = Wswz_u + H * H;               // 128*128 bf16, frag order
    float*          d_usr  = (float*)(Wswz_f + H * H);     // 128 f32

    prep_kernel<<<32, 64, 0, stream>>>(W1, b1, gamma, beta, rm, rv,
                                       Wswz_u, Wswz_f, d_usr);

    // persistent: ~2 blocks/CU, 2:1 user:food split matches row ratio
    const int GU = 342, GB = 512;
    proj_mfma<<<GB, 256, 0, stream>>>(z_user, z_food, Wswz_u, Wswz_f, d_usr,
                                      U, F, n_users, n_foods, GU, GB);

    edge_kernel<<<8192, 256, 0, stream>>>(U, F, row, col, W2, b2, out, E);
}